// Round 8
// baseline (384.408 us; speedup 1.0000x reference)
//
#include <hip/hip_runtime.h>
#include <hip/hip_bf16.h>
#include <stdint.h>

// Problem constants (from reference)
#define N_NODES 100000
#define N_EDGES 1600000
#define D_NODE  32
#define D_EDGE  16
#define D_IN    48   // D_NODE + D_EDGE
#define D_HID   64
#define D_OUT   32

// ---------------- workspace layout (bytes) ----------------
#define NFLAGS_OFF  ((size_t)0)         // 2 ints: {is_bf16, is_int64}
#define NB1_OFF     ((size_t)64)        // fp32 [64]
#define NB2_OFF     ((size_t)320)       // fp32 [32]
#define W1BF_OFF    ((size_t)1024)      // bf16 [n=64][k=64] n-major, k>=48 zero
#define W2BF_OFF    ((size_t)9216)      // bf16 [n=32][k=64] n-major
#define COUNTS_OFF  ((size_t)65536)     // int [N_NODES]
#define OFFSETS_OFF ((size_t)466944)    // int [N_NODES+1]
#define BLKSUM_OFF  ((size_t)917504)    // int [512]
#define RANK_OFF    ((size_t)1048576)   // int [N_EDGES]  (6.4 MB, ends < 8 MB)
#define MSG_OFF     ((size_t)8388608)   // bf16 message rows, 64 B each

#define SCAN_NB 391   // ceil(100000/256)

typedef __attribute__((ext_vector_type(8))) short bf16x8;   // 8 bf16 = 4 VGPRs
typedef __attribute__((ext_vector_type(4))) float f32x4;

__device__ inline float bf2f(unsigned int u16) {
    return __uint_as_float(u16 << 16);
}
__device__ inline unsigned short f2bf_rne(float f) {
    unsigned int x = __float_as_uint(f);
    unsigned int r = (x + 0x7FFFu + ((x >> 16) & 1u)) >> 16;
    return (unsigned short)r;
}
// packed RNE fp32x2 -> bf16x2 (v_cvt_pk_bf16_f32 on gfx950)
__device__ inline unsigned int pk_bf2(float a, float b) {
    float2 f; f.x = a; f.y = b;
    __hip_bfloat162 h = __float22bfloat162_rn(f);
    return *reinterpret_cast<unsigned int*>(&h);
}
__device__ inline float ld_f(const void* p, int i, int isbf) {
    if (isbf) return bf2f(((const unsigned short*)p)[i]);
    return ((const float*)p)[i];
}
__device__ inline bf16x8 pack_bf8(float4 v0, float4 v1) {
    union { unsigned int u[4]; bf16x8 v; } r;
    r.u[0] = pk_bf2(v0.x, v0.y);
    r.u[1] = pk_bf2(v0.z, v0.w);
    r.u[2] = pk_bf2(v1.x, v1.y);
    r.u[3] = pk_bf2(v1.z, v1.w);
    return r.v;
}

// ---------------------------------------------------------------------------
// Prep (grid-wide): every block zeroes its slice of counts; block 0 detects
// dtypes (ballot) and builds bf16 n-major weights + fp32 biases.
// ---------------------------------------------------------------------------
__global__ __launch_bounds__(256) void prep_kernel(
        const void* __restrict__ xq, const void* __restrict__ idxq,
        const void* __restrict__ W1q, const void* __restrict__ b1q,
        const void* __restrict__ W2q, const void* __restrict__ b2q,
        char* __restrict__ ws) {
    const int t = threadIdx.x;
    const int i0 = blockIdx.x * 256 + t;
    int* counts = (int*)(ws + COUNTS_OFF);
    if (i0 < N_NODES) counts[i0] = 0;
    if (blockIdx.x != 0) return;

    __shared__ int s_isbf;
    if (t < 64) {   // wave 0: parallel dtype detection
        unsigned short u = ((const unsigned short*)xq)[t];
        unsigned long long mb = __ballot(((u >> 7) & 0xFF) >= 140);
        int wodd = ((const int*)idxq)[2 * t + 1];
        unsigned long long mi = __ballot(wodd != 0);
        if (t == 0) {
            int* flags = (int*)(ws + NFLAGS_OFF);
            flags[0] = (mb == 0ULL);   // no big exponents -> genuine bf16
            flags[1] = (mi == 0ULL);   // all odd words zero -> int64
            s_isbf = (mb == 0ULL);
        }
    }
    __syncthreads();
    const int isbf = s_isbf;
    float* b1 = (float*)(ws + NB1_OFF);
    float* b2 = (float*)(ws + NB2_OFF);
    unsigned short* w1b = (unsigned short*)(ws + W1BF_OFF);
    unsigned short* w2b = (unsigned short*)(ws + W2BF_OFF);

    if (t < D_HID) b1[t] = ld_f(b1q, t, isbf);
    if (t < D_OUT) b2[t] = ld_f(b2q, t, isbf);

    // w1b[n][k] = W1[k][n] (k>=48 zero);  w2b[n][k] = W2[k][n]
    for (int i = t; i < D_HID * 64; i += 256) {
        int n = i >> 6, k = i & 63;
        float v = (k < D_IN) ? ld_f(W1q, k * D_HID + n, isbf) : 0.0f;
        w1b[i] = f2bf_rne(v);
    }
    for (int i = t; i < D_OUT * 64; i += 256) {
        int n = i >> 6, k = i & 63;
        w2b[i] = f2bf_rne(ld_f(W2q, k * D_OUT + n, isbf));
    }
}

// ---------------------------------------------------------------------------
// Histogram + per-edge rank (atomic return value); coalesced 4B/edge write.
// ---------------------------------------------------------------------------
__global__ __launch_bounds__(256) void hist_kernel(const void* __restrict__ idxq,
                                                   char* __restrict__ ws,
                                                   int* __restrict__ rankb) {
    const int is64 = ((const int*)(ws + NFLAGS_OFF))[1];
    const int e = blockIdx.x * 256 + threadIdx.x;
    int dst;
    if (is64) dst = (int)((const long long*)idxq)[e];
    else      dst = ((const int*)idxq)[e];
    rankb[e] = atomicAdd((int*)(ws + COUNTS_OFF) + dst, 1);
}

__global__ __launch_bounds__(256) void scan_block_kernel(char* __restrict__ ws) {
    __shared__ int s[256];
    const int* counts = (const int*)(ws + COUNTS_OFF);
    int* offs   = (int*)(ws + OFFSETS_OFF);
    int* blksum = (int*)(ws + BLKSUM_OFF);
    const int t = threadIdx.x;
    const int i = blockIdx.x * 256 + t;
    int v = (i < N_NODES) ? counts[i] : 0;
    s[t] = v;
    __syncthreads();
    for (int d = 1; d < 256; d <<= 1) {
        int a = (t >= d) ? s[t - d] : 0;
        __syncthreads();
        s[t] += a;
        __syncthreads();
    }
    if (i < N_NODES) offs[i] = s[t] - v;      // local exclusive
    if (t == 255) blksum[blockIdx.x] = s[255];
}

// scan_add with built-in top-level prefix: block b sums blksum[0..b-1] itself
// (391 ints from L2), then adds to its offsets.
__global__ __launch_bounds__(256) void scan_add_kernel(char* __restrict__ ws) {
    __shared__ int s[256];
    int* offs = (int*)(ws + OFFSETS_OFF);
    const int* blksum = (const int*)(ws + BLKSUM_OFF);
    const int t = threadIdx.x;
    const int b = blockIdx.x;
    int acc = 0;
    for (int j = t; j < b; j += 256) acc += blksum[j];
    s[t] = acc;
    __syncthreads();
    for (int d = 128; d > 0; d >>= 1) {
        if (t < d) s[t] += s[t + d];
        __syncthreads();
    }
    const int prefix = s[0];
    const int i = b * 256 + t;
    if (i < N_NODES) offs[i] += prefix;
    if (i == 0) offs[N_NODES] = N_EDGES;
}

// ---------------------------------------------------------------------------
// MFMA edge MLP v5. Block = 256 = 4 independent waves; wave owns 64 edges =
// 4 groups of 16 processed in a ROLLED loop (#pragma unroll 1) with a 1-deep
// A-fragment prefetch and a SINGLE per-wave [16][72] LDS buffer (9.2 KB/blk).
// Rationale: r5-r7's fully-unrolled bodies (~20KB code) correlate with the
// 30%-occupancy/17%-VALU plateau -> suspected L1I thrash; rolling shrinks
// the hot body ~4x. Per-group math is byte-identical to the verified r7 path.
// No __syncthreads (per-wave DS ordering). No atomics (pos=offs[dst]+rank).
// ---------------------------------------------------------------------------
__global__ __launch_bounds__(256) void edge_mlp_mfma_kernel(
        const void* __restrict__ xq,
        const void* __restrict__ idxq,
        const void* __restrict__ eaq,
        const char* __restrict__ wsro,
        const int* __restrict__ rankb,
        unsigned short* __restrict__ msg) {
    const int isbf = ((const int*)(wsro + NFLAGS_OFF))[0];
    const int is64 = ((const int*)(wsro + NFLAGS_OFF))[1];

    __shared__ __align__(16) unsigned short hbuf[4][16][72];

    const int w   = threadIdx.x >> 6;
    const int l   = threadIdx.x & 63;
    const int m16 = l & 15;
    const int q   = l >> 4;

    const unsigned short* w1b = (const unsigned short*)(wsro + W1BF_OFF);
    const unsigned short* w2b = (const unsigned short*)(wsro + W2BF_OFF);
    const float* b1 = (const float*)(wsro + NB1_OFF);
    const float* b2 = (const float*)(wsro + NB2_OFF);
    const int* offs = (const int*)(wsro + OFFSETS_OFF);

    // B-fragments: B[k=q*8+j][n=t*16+m16] = w?b[n][k] -> 16B loads (L1-hot)
    bf16x8 w1f[4][2], w2f[2][2];
#pragma unroll
    for (int t = 0; t < 4; ++t)
#pragma unroll
        for (int c = 0; c < 2; ++c)
            w1f[t][c] = *(const bf16x8*)(w1b + ((t * 16 + m16) * 64 + c * 32 + q * 8));
#pragma unroll
    for (int t = 0; t < 2; ++t)
#pragma unroll
        for (int c = 0; c < 2; ++c)
            w2f[t][c] = *(const bf16x8*)(w2b + ((t * 16 + m16) * 64 + c * 32 + q * 8));

    const int eb = blockIdx.x * 256 + w * 64;

    // indices + pos for all 4 groups (coalesced, issued up front)
    int srcv[4], posv[4];
#pragma unroll
    for (int g = 0; g < 4; ++g) {
        const int e = eb + g * 16 + m16;
        int dst;
        if (is64) {
            const long long* ip = (const long long*)idxq;
            dst = (int)ip[e];
            srcv[g] = (int)ip[N_EDGES + e];
        } else {
            const int* ip = (const int*)idxq;
            dst = ip[e];
            srcv[g] = ip[N_EDGES + e];
        }
        posv[g] = offs[dst] + rankb[e];
    }

    const float b1v[4] = { b1[m16], b1[16 + m16], b1[32 + m16], b1[48 + m16] };
    const float b2v[2] = { b2[m16], b2[16 + m16] };
    const int mrow = l >> 2;
    const int sub  = l & 3;

    // A-fragment loader (A1 uses (q&1): lanes q>=2 feed k=48..63 whose W1
    // rows are zero -> garbage multiplies to exactly 0)
    auto loadA = [&](int g, bf16x8& a0, bf16x8& a1) {
        const int e = eb + g * 16 + m16;
        if (isbf) {
            const unsigned short* x  = (const unsigned short*)xq;
            const unsigned short* ea = (const unsigned short*)eaq;
            a0 = *(const bf16x8*)(x + (size_t)srcv[g] * D_NODE + q * 8);
            a1 = *(const bf16x8*)(ea + (size_t)e * D_EDGE + (q & 1) * 8);
        } else {
            const float* x  = (const float*)xq;
            const float* ea = (const float*)eaq;
            const float4* xp = (const float4*)(x + (size_t)srcv[g] * D_NODE + q * 8);
            a0 = pack_bf8(xp[0], xp[1]);
            const float4* ap = (const float4*)(ea + (size_t)e * D_EDGE + (q & 1) * 8);
            a1 = pack_bf8(ap[0], ap[1]);
        }
    };

    bf16x8 A0c, A1c, A0n, A1n;
    loadA(0, A0c, A1c);

#pragma unroll 1
    for (int g = 0; g < 4; ++g) {
        if (g < 3) loadA(g + 1, A0n, A1n);     // 1-deep prefetch (uniform branch)

        // ---- layer 1: relu([16x48(pad64)] @ [48x64] + b1) -> hbuf ----
#pragma unroll
        for (int t = 0; t < 4; ++t) {
            f32x4 c;
            c[0] = c[1] = c[2] = c[3] = b1v[t];
            c = __builtin_amdgcn_mfma_f32_16x16x32_bf16(A0c, w1f[t][0], c, 0, 0, 0);
            c = __builtin_amdgcn_mfma_f32_16x16x32_bf16(A1c, w1f[t][1], c, 0, 0, 0);
            // C layout: row(m)=q*4+r, col(n)=t*16+m16
            unsigned int u0 = pk_bf2(fmaxf(c[0], 0.0f), fmaxf(c[1], 0.0f));
            unsigned int u1 = pk_bf2(fmaxf(c[2], 0.0f), fmaxf(c[3], 0.0f));
            hbuf[w][q * 4 + 0][t * 16 + m16] = (unsigned short)u0;
            hbuf[w][q * 4 + 1][t * 16 + m16] = (unsigned short)(u0 >> 16);
            hbuf[w][q * 4 + 2][t * 16 + m16] = (unsigned short)u1;
            hbuf[w][q * 4 + 3][t * 16 + m16] = (unsigned short)(u1 >> 16);
        }

        // ---- layer 2: [16x32] = [16x64] @ [64x32] + b2 (h read in A-layout)
        bf16x8 a20 = *(const bf16x8*)(&hbuf[w][m16][q * 8]);
        bf16x8 a21 = *(const bf16x8*)(&hbuf[w][m16][32 + q * 8]);
#pragma unroll
        for (int t = 0; t < 2; ++t) {
            f32x4 c;
            c[0] = c[1] = c[2] = c[3] = b2v[t];
            c = __builtin_amdgcn_mfma_f32_16x16x32_bf16(a20, w2f[t][0], c, 0, 0, 0);
            c = __builtin_amdgcn_mfma_f32_16x16x32_bf16(a21, w2f[t][1], c, 0, 0, 0);
            unsigned int u0 = pk_bf2(c[0], c[1]);
            unsigned int u1 = pk_bf2(c[2], c[3]);
            hbuf[w][q * 4 + 0][t * 16 + m16] = (unsigned short)u0;
            hbuf[w][q * 4 + 1][t * 16 + m16] = (unsigned short)(u0 >> 16);
            hbuf[w][q * 4 + 2][t * 16 + m16] = (unsigned short)u1;
            hbuf[w][q * 4 + 3][t * 16 + m16] = (unsigned short)(u1 >> 16);
        }

        // ---- row store: 4 lanes x 16B = one 64B row at rank position ----
        const int posm = __shfl(posv[g], mrow, 64);
        uint4 rowv = *(const uint4*)(&hbuf[w][mrow][sub * 8]);
        *(uint4*)(msg + (size_t)posm * D_OUT + sub * 8) = rowv;

        A0c = A0n; A1c = A1n;
    }
}

// ---------------------------------------------------------------------------
// Reduce v2: ONE WAVE PER NODE. 64 lanes load 16 rows/iteration (uint4/lane,
// coalesced 1KB), accumulate 8 fp32/lane across iterations (avg deg 16 ->
// ~1.4 iters), then a 4-step shfl_xor tree over the row dimension; lanes
// r==0 (4 lanes) store the 128B output row. Output dtype follows isbf.
// ---------------------------------------------------------------------------
__global__ __launch_bounds__(256) void reduce_kernel(
        const char* __restrict__ wsro, const unsigned short* __restrict__ msg,
        void* __restrict__ out) {
    const int isbf = ((const int*)(wsro + NFLAGS_OFF))[0];
    const int* offs = (const int*)(wsro + OFFSETS_OFF);
    const int node = (blockIdx.x * 256 + threadIdx.x) >> 6;   // wave id
    if (node >= N_NODES) return;
    const int l   = threadIdx.x & 63;
    const int r   = l >> 2;     // row within 16-chunk
    const int sub = l & 3;      // 16B quarter within the 64B row

    const int lo = offs[node], hi = offs[node + 1];
    float a0 = 0.f, a1 = 0.f, a2 = 0.f, a3 = 0.f,
          a4 = 0.f, a5 = 0.f, a6 = 0.f, a7 = 0.f;
    for (int k = lo; k < hi; k += 16) {
        const int row = k + r;
        if (row < hi) {
            uint4 v = *(const uint4*)(msg + (size_t)row * D_OUT + sub * 8);
            a0 += __uint_as_float(v.x << 16); a1 += __uint_as_float(v.x & 0xFFFF0000u);
            a2 += __uint_as_float(v.y << 16); a3 += __uint_as_float(v.y & 0xFFFF0000u);
            a4 += __uint_as_float(v.z << 16); a5 += __uint_as_float(v.z & 0xFFFF0000u);
            a6 += __uint_as_float(v.w << 16); a7 += __uint_as_float(v.w & 0xFFFF0000u);
        }
    }
    // reduce across rows: lane bits 2..5
#pragma unroll
    for (int mask = 4; mask <= 32; mask <<= 1) {
        a0 += __shfl_xor(a0, mask, 64); a1 += __shfl_xor(a1, mask, 64);
        a2 += __shfl_xor(a2, mask, 64); a3 += __shfl_xor(a3, mask, 64);
        a4 += __shfl_xor(a4, mask, 64); a5 += __shfl_xor(a5, mask, 64);
        a6 += __shfl_xor(a6, mask, 64); a7 += __shfl_xor(a7, mask, 64);
    }
    if (r == 0) {   // lanes 0..3 hold the final quarter-sums
        if (isbf) {
            uint4 p;
            p.x = pk_bf2(a0, a1); p.y = pk_bf2(a2, a3);
            p.z = pk_bf2(a4, a5); p.w = pk_bf2(a6, a7);
            *(uint4*)((unsigned short*)out + (size_t)node * D_OUT + sub * 8) = p;
        } else {
            float4* op = (float4*)((float*)out + (size_t)node * D_OUT + sub * 8);
            float4 v0; v0.x = a0; v0.y = a1; v0.z = a2; v0.w = a3;
            float4 v1; v1.x = a4; v1.y = a5; v1.z = a6; v1.w = a7;
            op[0] = v0;
            op[1] = v1;
        }
    }
}

extern "C" void kernel_launch(void* const* d_in, const int* in_sizes, int n_in,
                              void* d_out, int out_size, void* d_ws, size_t ws_size,
                              hipStream_t stream) {
    const void* x   = d_in[0];
    const void* idx = d_in[1];
    const void* ea  = d_in[2];
    const void* W1  = d_in[3];
    const void* b1  = d_in[4];
    const void* W2  = d_in[5];
    const void* b2  = d_in[6];
    char* ws = (char*)d_ws;

    hipLaunchKernelGGL(prep_kernel, dim3(SCAN_NB), dim3(256), 0, stream,
                       x, idx, W1, b1, W2, b2, ws);

    hipLaunchKernelGGL(hist_kernel, dim3(N_EDGES / 256), dim3(256), 0, stream,
                       idx, ws, (int*)(ws + RANK_OFF));

    hipLaunchKernelGGL(scan_block_kernel, dim3(SCAN_NB), dim3(256), 0, stream, ws);
    hipLaunchKernelGGL(scan_add_kernel,   dim3(SCAN_NB), dim3(256), 0, stream, ws);

    hipLaunchKernelGGL(edge_mlp_mfma_kernel, dim3(N_EDGES / 256), dim3(256), 0, stream,
                       x, idx, ea, (const char*)ws,
                       (const int*)(ws + RANK_OFF), (unsigned short*)(ws + MSG_OFF));

    hipLaunchKernelGGL(reduce_kernel, dim3((N_NODES + 3) / 4), dim3(256), 0, stream,
                       (const char*)ws, (const unsigned short*)(ws + MSG_OFF), d_out);
}